// Round 5
// baseline (955.011 us; speedup 1.0000x reference)
//
#include <hip/hip_runtime.h>

#define DK 256   // K dim of every GEMM (D_IN == D_HID == 256)
#define BSH 7    // bucket covers 128 consecutive dst nodes

typedef __attribute__((ext_vector_type(8))) short bf16x8;   // 8 bf16 in 4 VGPRs
typedef __attribute__((ext_vector_type(4))) float f32x4;

__device__ __forceinline__ unsigned short f2b(float f) {    // RNE fp32->bf16
    unsigned u = __builtin_bit_cast(unsigned, f);
    u += 0x7FFFu + ((u >> 16) & 1u);
    return (unsigned short)(u >> 16);
}
__device__ __forceinline__ float b2f(unsigned short s) {
    return __builtin_bit_cast(float, (unsigned)s << 16);
}
__device__ __forceinline__ void gld_lds16(void* lds, const void* g) {
    __builtin_amdgcn_global_load_lds(
        (const __attribute__((address_space(1))) unsigned int*)g,
        (__attribute__((address_space(3))) unsigned int*)lds, 16, 0, 0);
}

// ---------------------------------------------------------------------------
// fp32 -> bf16 conversion, 4 elems/thread (bulk x)
// ---------------------------------------------------------------------------
__global__ __launch_bounds__(256) void k_cvt(const float* __restrict__ src,
                                             unsigned short* __restrict__ dst, int n4) {
    int i = blockIdx.x * 256 + threadIdx.x;
    if (i < n4) {
        float4 v = reinterpret_cast<const float4*>(src)[i];
        ushort4 o = make_ushort4(f2b(v.x), f2b(v.y), f2b(v.z), f2b(v.w));
        reinterpret_cast<ushort4*>(dst)[i] = o;
    }
}

// all four weight matrices in one launch (49152 float4 quads total)
__global__ __launch_bounds__(256) void k_cvtW(const float* __restrict__ a,
                                              const float* __restrict__ b,
                                              const float* __restrict__ c,
                                              const float* __restrict__ d,
                                              unsigned short* __restrict__ Wb1,
                                              unsigned short* __restrict__ Wb2) {
    int i = blockIdx.x * 256 + threadIdx.x;
    const float* s; unsigned short* o; int j;
    if (i < 16384)      { s = a; o = Wb1;         j = i; }
    else if (i < 32768) { s = b; o = Wb1 + 65536; j = i - 16384; }
    else if (i < 40960) { s = c; o = Wb2;         j = i - 32768; }
    else                { s = d; o = Wb2 + 32768; j = i - 40960; }
    float4 v = reinterpret_cast<const float4*>(s)[j];
    reinterpret_cast<ushort4*>(o)[j] = make_ushort4(f2b(v.x), f2b(v.y), f2b(v.z), f2b(v.w));
}

// ---------------------------------------------------------------------------
// CSR build
// ---------------------------------------------------------------------------
__global__ __launch_bounds__(256) void k_deg_i(const int* __restrict__ dst,
                                               int* __restrict__ degi, int E) {
    int e = blockIdx.x * 256 + threadIdx.x;
    if (e < E) atomicAdd(degi + dst[e], 1);
}

// device-wide exclusive scan over degi (3 kernels, 1024 elems/block)
__global__ __launch_bounds__(256) void k_scan_a(const int* __restrict__ degi,
                                                int* __restrict__ bsum, int N) {
    __shared__ int sm[256];
    int t = threadIdx.x;
    int i0 = blockIdx.x * 1024 + t * 4;
    int s = 0;
    if (i0 + 3 < N) {
        int4 v = *reinterpret_cast<const int4*>(degi + i0);
        s = v.x + v.y + v.z + v.w;
    } else {
        for (int i = i0; i < min(i0 + 4, N); ++i) s += degi[i];
    }
    sm[t] = s;
    __syncthreads();
    for (int off = 128; off > 0; off >>= 1) {
        if (t < off) sm[t] += sm[t + off];
        __syncthreads();
    }
    if (t == 0) bsum[blockIdx.x] = sm[0];
}

__global__ __launch_bounds__(256) void k_scan_b(const int* __restrict__ bsum,
                                                int* __restrict__ boff,
                                                int* __restrict__ rowptrN, int NB) {
    __shared__ int sm[256];
    int t = threadIdx.x;
    sm[t] = (t < NB) ? bsum[t] : 0;
    __syncthreads();
    for (int off = 1; off < 256; off <<= 1) {
        int v = (t >= off) ? sm[t - off] : 0;
        __syncthreads();
        sm[t] += v;
        __syncthreads();
    }
    if (t < NB) boff[t] = (t == 0) ? 0 : sm[t - 1];
    if (t == NB - 1) *rowptrN = sm[t];
}

// writes rowptr, invdeg, and per-bucket base cursors (bcur)
__global__ __launch_bounds__(256) void k_scan_c(const int* __restrict__ degi,
                                                const int* __restrict__ boff,
                                                int* __restrict__ rowptr,
                                                int* __restrict__ bcur,
                                                float* __restrict__ invdeg, int N) {
    __shared__ int sm[256];
    int t = threadIdx.x;
    int i0 = blockIdx.x * 1024 + t * 4;
    int d0 = 0, d1 = 0, d2 = 0, d3 = 0;
    if (i0 + 3 < N) {
        int4 v = *reinterpret_cast<const int4*>(degi + i0);
        d0 = v.x; d1 = v.y; d2 = v.z; d3 = v.w;
    } else {
        if (i0 + 0 < N) d0 = degi[i0 + 0];
        if (i0 + 1 < N) d1 = degi[i0 + 1];
        if (i0 + 2 < N) d2 = degi[i0 + 2];
        if (i0 + 3 < N) d3 = degi[i0 + 3];
    }
    int s = d0 + d1 + d2 + d3;
    sm[t] = s;
    __syncthreads();
    for (int off = 1; off < 256; off <<= 1) {
        int v = (t >= off) ? sm[t - off] : 0;
        __syncthreads();
        sm[t] += v;
        __syncthreads();
    }
    int run = boff[blockIdx.x] + sm[t] - s;    // exclusive prefix of this thread
    int dd[4] = {d0, d1, d2, d3};
#pragma unroll
    for (int i = 0; i < 4; ++i) {
        int idx = i0 + i;
        if (idx < N) {
            rowptr[idx] = run;
            if ((idx & ((1 << BSH) - 1)) == 0) bcur[idx >> BSH] = run;
            invdeg[idx] = 1.0f / fmaxf((float)dd[i], 1.0f);
            run += dd[i];
        }
    }
}

// phase A: append packed (src, dst_local) into CSR-aligned bucket regions
__global__ __launch_bounds__(256) void k_bucket(const int* __restrict__ src,
                                                const int* __restrict__ dst,
                                                int* __restrict__ bcur,
                                                unsigned* __restrict__ bucket, int E) {
    int e = blockIdx.x * 256 + threadIdx.x;
    if (e < E) {
        int d = dst[e], s = src[e];
        int b = d >> BSH;
        int p = atomicAdd(bcur + b, 1);
        bucket[p] = ((unsigned)s << BSH) | (unsigned)(d & ((1 << BSH) - 1));
    }
}

// phase B: one block per bucket; LDS cursors; col writes land in an 8KB window
__global__ __launch_bounds__(256) void k_place(const unsigned* __restrict__ bucket,
                                               const int* __restrict__ rowptr,
                                               int* __restrict__ col, int N) {
    __shared__ int cur[1 << BSH];
    int b = blockIdx.x;
    int n0 = b << BSH;
    int t = threadIdx.x;
    if (t < (1 << BSH)) cur[t] = rowptr[min(n0 + t, N)];
    __syncthreads();
    int beg = rowptr[min(n0, N)];
    int end = rowptr[min(n0 + (1 << BSH), N)];
    for (int i = beg + t; i < end; i += 256) {
        unsigned p = bucket[i];
        int dl = p & ((1 << BSH) - 1);
        int s  = (int)(p >> BSH);
        int pos = atomicAdd(&cur[dl], 1);
        col[pos] = s;
    }
}

// ---------------------------------------------------------------------------
// bf16 MFMA GEMM (m97 recipe): C[m,n] = A[m,:]·W[n,:], K=256.
// 128x128 tile, 256 thr = 4 waves (2x2), each wave 4x4 grid of 16x16x32 MFMA.
// Output split: cols [0,DOUTA) -> Y (bf16); cols [DOUTA,2*DOUTA) -> R.
// ---------------------------------------------------------------------------
template <bool RF32>
__global__ __launch_bounds__(256) void k_gemm_bf16(const unsigned short* __restrict__ A,
                                                   const unsigned short* __restrict__ W,
                                                   unsigned short* __restrict__ Y,
                                                   void* __restrict__ Rv,
                                                   int DOUTA, int N) {
    __shared__ unsigned short As[128 * 32];   // [row][k] bf16, unpadded (global_load_lds)
    __shared__ unsigned short Bs[128 * 32];
    const int tid  = threadIdx.x;
    const int lane = tid & 63;
    const int w    = tid >> 6;
    const int wm   = w & 1, wn = w >> 1;
    const int m0   = blockIdx.x * 128;
    const int n0   = blockIdx.y * 128;
    const int lm   = lane & 15, quad = lane >> 4;

    f32x4 acc[4][4];
#pragma unroll
    for (int i = 0; i < 4; ++i)
#pragma unroll
        for (int j = 0; j < 4; ++j) acc[i][j] = (f32x4){0.f, 0.f, 0.f, 0.f};

    const int srow  = lane >> 2;        // row within 16-row chunk
    const int skoff = (lane & 3) * 8;   // bf16 offset within 32-wide k slice
    const int ca = 2 * w, cb = 2 * w + 1;

    for (int k0 = 0; k0 < DK; k0 += 32) {
        int ra = min(m0 + 16 * ca + srow, N - 1);   // clamp M tail (stores masked)
        int rb = min(m0 + 16 * cb + srow, N - 1);
        gld_lds16(As + ca * 512, A + (size_t)ra * DK + k0 + skoff);
        gld_lds16(As + cb * 512, A + (size_t)rb * DK + k0 + skoff);
        int na = n0 + 16 * ca + srow;               // DOUT multiple of 128 -> in bounds
        int nb = n0 + 16 * cb + srow;
        gld_lds16(Bs + ca * 512, W + (size_t)na * DK + k0 + skoff);
        gld_lds16(Bs + cb * 512, W + (size_t)nb * DK + k0 + skoff);
        __syncthreads();

        bf16x8 af[4], bfr[4];
#pragma unroll
        for (int mt = 0; mt < 4; ++mt)
            af[mt] = *reinterpret_cast<const bf16x8*>(As + (wm * 64 + mt * 16 + lm) * 32 + quad * 8);
#pragma unroll
        for (int nt = 0; nt < 4; ++nt)
            bfr[nt] = *reinterpret_cast<const bf16x8*>(Bs + (wn * 64 + nt * 16 + lm) * 32 + quad * 8);
#pragma unroll
        for (int mt = 0; mt < 4; ++mt)
#pragma unroll
            for (int nt = 0; nt < 4; ++nt)
                acc[mt][nt] = __builtin_amdgcn_mfma_f32_16x16x32_bf16(af[mt], bfr[nt], acc[mt][nt], 0, 0, 0);
        __syncthreads();
    }

    const bool yPart = (n0 < DOUTA);
#pragma unroll
    for (int mt = 0; mt < 4; ++mt) {
#pragma unroll
        for (int nt = 0; nt < 4; ++nt) {
            int gn = n0 + wn * 64 + nt * 16 + lm;
#pragma unroll
            for (int reg = 0; reg < 4; ++reg) {
                int gm = m0 + wm * 64 + mt * 16 + quad * 4 + reg;
                if (gm < N) {
                    float v = acc[mt][nt][reg];
                    if (yPart) {
                        Y[(size_t)gm * DOUTA + gn] = f2b(v);
                    } else if (RF32) {
                        ((float*)Rv)[(size_t)gm * DOUTA + (gn - DOUTA)] = v;
                    } else {
                        ((unsigned short*)Rv)[(size_t)gm * DOUTA + (gn - DOUTA)] = f2b(v);
                    }
                }
            }
        }
    }
}

// ---------------------------------------------------------------------------
// layer-1 aggregate: H = relu(mean(Y[nbrs]) + bias + R), width 256
// ---------------------------------------------------------------------------
__global__ __launch_bounds__(256) void k_agg256(const unsigned short* __restrict__ Y,
                                                const unsigned short* __restrict__ Rb,
                                                const float* __restrict__ bias,
                                                const float* __restrict__ invdeg,
                                                const int* __restrict__ rowptr,
                                                const int* __restrict__ col,
                                                unsigned short* __restrict__ H, int N) {
    long long g = (long long)blockIdx.x * 256 + threadIdx.x;
    int node = (int)(g >> 6);
    int lane = (int)(g & 63);
    if (node >= N) return;
    int beg = rowptr[node], end = rowptr[node + 1];
    const unsigned short* yb = Y + lane * 4;
    float a0 = 0, a1 = 0, a2 = 0, a3 = 0;
    int e = beg;
    for (; e + 1 < end; e += 2) {
        int s0 = col[e], s1 = col[e + 1];
        ushort4 v0 = *reinterpret_cast<const ushort4*>(yb + (size_t)s0 * 256);
        ushort4 v1 = *reinterpret_cast<const ushort4*>(yb + (size_t)s1 * 256);
        a0 += b2f(v0.x) + b2f(v1.x);
        a1 += b2f(v0.y) + b2f(v1.y);
        a2 += b2f(v0.z) + b2f(v1.z);
        a3 += b2f(v0.w) + b2f(v1.w);
    }
    if (e < end) {
        ushort4 v0 = *reinterpret_cast<const ushort4*>(yb + (size_t)col[e] * 256);
        a0 += b2f(v0.x); a1 += b2f(v0.y); a2 += b2f(v0.z); a3 += b2f(v0.w);
    }
    float inv = invdeg[node];
    int c = lane * 4;
    ushort4 r = *reinterpret_cast<const ushort4*>(Rb + (size_t)node * 256 + c);
    float o0 = fmaxf(a0 * inv + bias[c + 0] + b2f(r.x), 0.f);
    float o1 = fmaxf(a1 * inv + bias[c + 1] + b2f(r.y), 0.f);
    float o2 = fmaxf(a2 * inv + bias[c + 2] + b2f(r.z), 0.f);
    float o3 = fmaxf(a3 * inv + bias[c + 3] + b2f(r.w), 0.f);
    *reinterpret_cast<ushort4*>(H + (size_t)node * 256 + c) =
        make_ushort4(f2b(o0), f2b(o1), f2b(o2), f2b(o3));
}

// ---------------------------------------------------------------------------
// layer-2 aggregate: O = mean(Y[nbrs]) + bias + R, width 128, fp32 out
// ---------------------------------------------------------------------------
__global__ __launch_bounds__(256) void k_agg128(const unsigned short* __restrict__ Y,
                                                const float* __restrict__ Rf,
                                                const float* __restrict__ bias,
                                                const float* __restrict__ invdeg,
                                                const int* __restrict__ rowptr,
                                                const int* __restrict__ col,
                                                float* __restrict__ O, int N) {
    long long g = (long long)blockIdx.x * 256 + threadIdx.x;
    int node = (int)(g >> 6);
    int lane = (int)(g & 63);
    if (node >= N) return;
    int beg = rowptr[node], end = rowptr[node + 1];
    const unsigned short* yb = Y + lane * 2;
    float a0 = 0, a1 = 0;
    int e = beg;
    for (; e + 1 < end; e += 2) {
        int s0 = col[e], s1 = col[e + 1];
        unsigned v0 = *reinterpret_cast<const unsigned*>(yb + (size_t)s0 * 128);
        unsigned v1 = *reinterpret_cast<const unsigned*>(yb + (size_t)s1 * 128);
        a0 += b2f((unsigned short)(v0 & 0xffff)) + b2f((unsigned short)(v1 & 0xffff));
        a1 += b2f((unsigned short)(v0 >> 16)) + b2f((unsigned short)(v1 >> 16));
    }
    if (e < end) {
        unsigned v0 = *reinterpret_cast<const unsigned*>(yb + (size_t)col[e] * 128);
        a0 += b2f((unsigned short)(v0 & 0xffff));
        a1 += b2f((unsigned short)(v0 >> 16));
    }
    float inv = invdeg[node];
    int c = lane * 2;
    float2 r = *reinterpret_cast<const float2*>(Rf + (size_t)node * 128 + c);
    float2 o;
    o.x = a0 * inv + bias[c + 0] + r.x;
    o.y = a1 * inv + bias[c + 1] + r.y;
    *reinterpret_cast<float2*>(O + (size_t)node * 128 + c) = o;
}

// ---------------------------------------------------------------------------
extern "C" void kernel_launch(void* const* d_in, const int* in_sizes, int n_in,
                              void* d_out, int out_size, void* d_ws, size_t ws_size,
                              hipStream_t stream) {
    const float* x   = (const float*)d_in[0];
    const int*   ei  = (const int*)d_in[1];
    const float* W1l = (const float*)d_in[2];
    const float* b1  = (const float*)d_in[3];
    const float* W1r = (const float*)d_in[4];
    const float* W2l = (const float*)d_in[5];
    const float* b2  = (const float*)d_in[6];
    const float* W2r = (const float*)d_in[7];
    float* out = (float*)d_out;

    const int N = in_sizes[0] / DK;   // 100000
    const int E = in_sizes[1] / 2;    // 1600000
    const int* src = ei;
    const int* dst = ei + E;

    // workspace:
    //   xb | y1b (y2b aliases) | r1b (r2f aliases) | hb (bucket aliases front 6.4MB)
    //   Wb1[512*256] Wb2[256*256] | invdeg | degi | rowptr | col | bsum | boff | bcur
    unsigned short* xb  = (unsigned short*)d_ws;
    unsigned short* y1b = xb + (size_t)N * 256;
    unsigned short* r1b = y1b + (size_t)N * 256;
    unsigned short* hb  = r1b + (size_t)N * 256;
    unsigned short* Wb1 = hb + (size_t)N * 256;
    unsigned short* Wb2 = Wb1 + 512 * 256;
    float* invdeg = (float*)(Wb2 + 256 * 256);
    int* degi   = (int*)(invdeg + N);
    int* rowptr = degi + N;              // N+1
    int* col    = rowptr + (N + 1);      // E
    int* bsum   = col + E;
    int* boff   = bsum + 512;
    int* bcur   = boff + 512;            // NBUK (<=1024)
    unsigned short* y2b = y1b;           // layer-2 aliases (lifetimes disjoint)
    float* r2f = (float*)r1b;
    unsigned* bucket = (unsigned*)hb;    // CSR-build lifetime only (pre-layer-1)

    // ---- conversions to bf16 ----
    k_cvt<<<(N * 64 + 255) / 256, 256, 0, stream>>>(x, xb, N * 64);
    k_cvtW<<<192, 256, 0, stream>>>(W1l, W1r, W2l, W2r, Wb1, Wb2);

    // ---- CSR build ----
    const int NB   = (N + 1023) / 1024;          // scan blocks (98)
    const int NBUK = (N + (1 << BSH) - 1) >> BSH; // buckets (782)
    hipMemsetAsync(degi, 0, (size_t)N * sizeof(int), stream);
    k_deg_i<<<(E + 255) / 256, 256, 0, stream>>>(dst, degi, E);
    k_scan_a<<<NB, 256, 0, stream>>>(degi, bsum, N);
    k_scan_b<<<1, 256, 0, stream>>>(bsum, boff, rowptr + N, NB);
    k_scan_c<<<NB, 256, 0, stream>>>(degi, boff, rowptr, bcur, invdeg, N);
    k_bucket<<<(E + 255) / 256, 256, 0, stream>>>(src, dst, bcur, bucket, E);
    k_place<<<NBUK, 256, 0, stream>>>(bucket, rowptr, col, N);

    int mTiles = (N + 127) / 128;       // 782
    int aggBlocks = (N + 3) / 4;        // 4 nodes (waves) per block

    // ---- layer 1 ----
    k_gemm_bf16<false><<<dim3(mTiles, 4), 256, 0, stream>>>(xb, Wb1, y1b, r1b, 256, N);
    k_agg256<<<aggBlocks, 256, 0, stream>>>(y1b, r1b, b1, invdeg, rowptr, col, hb, N);

    // ---- layer 2 ----
    k_gemm_bf16<true><<<dim3(mTiles, 2), 256, 0, stream>>>(hb, Wb2, y2b, r2f, 128, N);
    k_agg128<<<aggBlocks, 256, 0, stream>>>(y2b, r2f, b2, invdeg, rowptr, col, out, N);
}